// Round 9
// baseline (160.104 us; speedup 1.0000x reference)
//
#include <hip/hip_runtime.h>
#include <math.h>
#include <stdint.h>

// ---------------- model constants ----------------
#define BATCH 65536
#define TB 128           // rows per block: 2 waves x 64 rows (2 m-tiles each)

typedef __fp16   fp16x2  __attribute__((ext_vector_type(2)));   // cvt_pkrtz result
typedef _Float16 half8   __attribute__((ext_vector_type(8)));
typedef float    floatx16 __attribute__((ext_vector_type(16)));

// per-tile LDS strides (halves)
#define SH 68            // hH: 64 cols + 4 pad
#define SM 130           // hM: 129 cols + 1
#define HM_SLICE (32*SM + 64)   // +64 zeroed tail halves (b128 overrun, row 31)

// packed-weight geometry (f16), FRAGMENT-ORDERED for 32x32x16 (same as R0):
//   element (ks, nt, lane, j) at ((ks*NT + nt)*512) + lane*8 + j
//   maps to B[k = ks*16 + (lane>>5)*8 + j][n = nt*32 + (lane&31)]
#define WIN 2048          // stage1: 2 ksteps x 2 ntiles x 512
#define KSA 36            // a: 32 spline ksteps + 4 silu
#define KSB 74            // b: 65 spline ksteps (1032 real k) + 9 silu (129 real)
#define WA (KSA*5*512)    // 92160
#define WB (KSB*2*512)    // 75776
#define WTOT (WIN + 2*(WA+WB))   // 337920 halfs = 675840 B of d_ws

// ---------------------------------------------------------------------------
// setup: pack all weights f16 in 32x32-fragment order (unchanged from R0).
// ---------------------------------------------------------------------------
__global__ void setup_weights(
    const float* __restrict__ W_in,
    const float* __restrict__ c0a, const float* __restrict__ sb0a, const float* __restrict__ ss0a,
    const float* __restrict__ c0b, const float* __restrict__ sb0b, const float* __restrict__ ss0b,
    const float* __restrict__ c1a, const float* __restrict__ sb1a, const float* __restrict__ ss1a,
    const float* __restrict__ c1b, const float* __restrict__ sb1b, const float* __restrict__ ss1b,
    _Float16* __restrict__ wt) {
  int idx = blockIdx.x * 256 + threadIdx.x;
  if (idx >= WTOT) return;
  float v = 0.0f;
  if (idx < WIN) {                        // W_in [32][64]: (ks*2+nt)*512 order
    int ks = idx >> 10; int nt = (idx >> 9) & 1;
    int q = idx & 511;  int l = q >> 3;   int j = q & 7;
    int n = nt*32 + (l & 31);
    int k = ks*16 + (l >> 5)*8 + j;
    v = W_in[k*64 + n];
  } else {
    int e2   = idx - WIN;
    int pair = (e2 >= WA + WB) ? 1 : 0;
    int e    = e2 - pair * (WA + WB);
    if (e < WA) {                         // a-type: I=64, O=129 (5 n-tiles)
      const float* coef = pair ? c1a : c0a;
      const float* sb   = pair ? sb1a : sb0a;
      const float* ss   = pair ? ss1a : ss0a;
      int ks = e / 2560; int r = e - ks*2560;
      int nt = r >> 9;   int q = r & 511;
      int l  = q >> 3;   int j = q & 7;
      int n  = nt*32 + (l & 31);
      int k  = ks*16 + (l >> 5)*8 + j;    // k < 576
      if (n < 129) {
        if (k < 512) { int i = k >> 3, p = k & 7; v = ss[i*129+n] * coef[(i*129+n)*8 + p]; }
        else         { int i = k - 512; if (i < 64) v = sb[i*129+n]; }
      }
    } else {                              // b-type: I=129, O=64 (2 n-tiles)
      const float* coef = pair ? c1b : c0b;
      const float* sb   = pair ? sb1b : sb0b;
      const float* ss   = pair ? ss1b : ss0b;
      int eb = e - WA;
      int ks = eb >> 10; int r = eb & 1023;
      int nt = r >> 9;   int q = r & 511;
      int l  = q >> 3;   int j = q & 7;
      int n  = nt*32 + (l & 31);
      int k  = ks*16 + (l >> 5)*8 + j;    // k < 1184
      if (k < 1032)      { int i = k >> 3, p = k & 7; v = ss[i*64+n] * coef[(i*64+n)*8 + p]; }
      else if (k >= 1040){ int s = k - 1040; if (s < 129) v = sb[s*64+n]; }
      // k in [1032,1040) and s >= 129: dead pad slots -> 0
    }
  }
  wt[idx] = (_Float16)v;
}

// ---------------------------------------------------------------------------
// feat8: 8 B-spline basis values of x as a ready A-fragment (R0, unchanged).
// ---------------------------------------------------------------------------
__device__ __forceinline__ half8 feat8(float x) {
  float s  = fmaf(x, 2.5f, 5.5f);          // (x+2.2)*2.5
  float mf = floorf(s);
  int   m  = (int)mf;
  float u  = s - mf;
  float t  = 1.0f - u;
  float u2 = u*u;
  float t2 = t*t;
  float w0 = t2 * (t * (1.0f/6.0f));
  float w3 = u2 * (u * (1.0f/6.0f));
  float w1 = fmaf(u2, fmaf(0.5f, u, -1.0f), 2.0f/3.0f);   // (3u^3-6u^2+4)/6
  float w2 = fmaf(t2, fmaf(0.5f, t, -1.0f), 2.0f/3.0f);   // symmetry: w1(t)
  union { fp16x2 h2[2]; uint64_t u64; } P;
  P.h2[0] = __builtin_amdgcn_cvt_pkrtz(w0, w1);
  P.h2[1] = __builtin_amdgcn_cvt_pkrtz(w2, w3);
  uint64_t T = ((unsigned)m <= 10u) ? P.u64 : 0ull;
  int A = (m << 4) - 48;                   // bit pos of T in 128-bit window
  uint64_t L  = T << (A & 63);             // valid A: {-48..112} step 16
  uint64_t R_ = T >> ((-A) & 63);
  uint64_t q0 = (A >= 0) ? ((A < 64) ? L : 0ull) : R_;
  uint64_t q1 = (A >= 64) ? L : ((A > 0) ? R_ : 0ull);
  union { uint64_t q[2]; half8 h; } R;
  R.q[0] = q0; R.q[1] = q1;
  return R.h;
}

// extract half #kh of dword w (khs = kh*16), as f32
__device__ __forceinline__ float extract_half(uint32_t w, int khs) {
  union { uint32_t u; _Float16 h[2]; } cv;
  cv.u = w >> khs;
  return (float)cv.h[0];
}

// cheap silu: x * rcp(1+exp(-x))
__device__ __forceinline__ float silu(float x) {
  return x * __builtin_amdgcn_rcpf(1.0f + __expf(-x));
}

// ---------------------------------------------------------------------------
// one KAN layer, per-wave 64 rows = TWO 32x32 m-tiles sharing one B stream.
// Per kstep: B loaded ONCE (NT b128), consumed by 2 A-fragments -> 2*NT MFMAs.
// Halves per-CU VMEM requests vs R0; doubles per-wave ILP. Depth-2 zero-copy
// B pipeline (R3 proved deeper is null). Accumulation order per row = R0.
// ---------------------------------------------------------------------------
template<int KSPL, int KSIL, int NT, int SIN, int O, int SOUT>
__device__ __forceinline__ void kan_layer2(
    const _Float16* __restrict__ hin0, const _Float16* __restrict__ hin1,
    _Float16* __restrict__ hout0, _Float16* __restrict__ hout1,
    const _Float16* __restrict__ wt, const float* __restrict__ bias, int lane) {
  constexpr int KTOT = KSPL + KSIL;
  constexpr int NG   = KSPL / 8;            // full spline groups
  constexpr int KR   = KSPL - NG*8;         // remainder spline steps (0 or 1)
  static_assert(KR == 0 || KR == 1, "remainder must be 0/1");
  const int ln  = lane & 31;
  const int kh  = lane >> 5;
  const int khs = kh << 4;
  const half8* __restrict__ bp = (const half8*)wt + lane;   // +lane*16B
  floatx16 acc0[NT], acc1[NT];
  #pragma unroll
  for (int j = 0; j < NT; ++j)
    #pragma unroll
    for (int e = 0; e < 16; ++e) { acc0[j][e] = 0.0f; acc1[j][e] = 0.0f; }

  half8 B[2][NT];                           // depth-2, zero-copy slots (SHARED)
  #pragma unroll
  for (int d = 0; d < 2; ++d)
    #pragma unroll
    for (int j = 0; j < NT; ++j) B[d][j] = bp[(d*NT + j)*64];

  union H8 { half8 h; uint32_t d[4]; };

  // ---- spline groups: 8 k-steps each; inputs 16g..16g+15 per tile ----
  #pragma unroll 1
  for (int g = 0; g < NG; ++g) {
    H8 ha0, hb0, ha1, hb1;
    ha0.h = *(const half8*)&hin0[ln*SIN + g*16];
    hb0.h = *(const half8*)&hin0[ln*SIN + g*16 + 8];
    ha1.h = *(const half8*)&hin1[ln*SIN + g*16];
    hb1.h = *(const half8*)&hin1[ln*SIN + g*16 + 8];
    #pragma unroll
    for (int u = 0; u < 8; ++u) {
      uint32_t w0 = (u < 4) ? ha0.d[u] : hb0.d[u & 3];
      uint32_t w1 = (u < 4) ? ha1.d[u] : hb1.d[u & 3];
      half8 A0 = feat8(extract_half(w0, khs));     // tile0 input i = 2(g*8+u)+kh
      half8 A1 = feat8(extract_half(w1, khs));     // tile1 same i
      #pragma unroll
      for (int j = 0; j < NT; ++j)
        acc0[j] = __builtin_amdgcn_mfma_f32_32x32x16_f16(A0, B[u & 1][j], acc0[j], 0, 0, 0);
      #pragma unroll
      for (int j = 0; j < NT; ++j)
        acc1[j] = __builtin_amdgcn_mfma_f32_32x32x16_f16(A1, B[u & 1][j], acc1[j], 0, 0, 0);
      #pragma unroll
      for (int j = 0; j < NT; ++j)               // refill same slot with ks+2
        B[u & 1][j] = bp[((g*8 + u + 2)*NT + j)*64];
    }
  }

  // ---- remainder spline step (layer-b: ks = NG*8) ----
  if (KR == 1) {
    constexpr int ks = NG*8;
    uint32_t w0 = *(const uint32_t*)&hin0[ln*SIN + ks*2];
    uint32_t w1 = *(const uint32_t*)&hin1[ln*SIN + ks*2];
    half8 A0 = feat8(extract_half(w0, khs));
    half8 A1 = feat8(extract_half(w1, khs));
    #pragma unroll
    for (int j = 0; j < NT; ++j)
      acc0[j] = __builtin_amdgcn_mfma_f32_32x32x16_f16(A0, B[ks & 1][j], acc0[j], 0, 0, 0);
    #pragma unroll
    for (int j = 0; j < NT; ++j)
      acc1[j] = __builtin_amdgcn_mfma_f32_32x32x16_f16(A1, B[ks & 1][j], acc1[j], 0, 0, 0);
    #pragma unroll
    for (int j = 0; j < NT; ++j)
      B[ks & 1][j] = bp[((ks + 2)*NT + j)*64];   // ks+2 < KTOT (KSIL >= 9 here)
  }

  // ---- silu k-steps (fully unrolled; slots compile-time) ----
  #pragma unroll
  for (int sk = 0; sk < KSIL; ++sk) {
    const int ks = KSPL + sk;
    half8 h80 = *(const half8*)&hin0[ln*SIN + sk*16 + kh*8];
    half8 h81 = *(const half8*)&hin1[ln*SIN + sk*16 + kh*8];
    union { fp16x2 h2[4]; half8 v; } Au0, Au1;
    #pragma unroll
    for (int e = 0; e < 4; ++e) {
      Au0.h2[e] = __builtin_amdgcn_cvt_pkrtz(silu((float)h80[2*e]), silu((float)h80[2*e + 1]));
      Au1.h2[e] = __builtin_amdgcn_cvt_pkrtz(silu((float)h81[2*e]), silu((float)h81[2*e + 1]));
    }
    #pragma unroll
    for (int j = 0; j < NT; ++j)
      acc0[j] = __builtin_amdgcn_mfma_f32_32x32x16_f16(Au0.v, B[ks & 1][j], acc0[j], 0, 0, 0);
    #pragma unroll
    for (int j = 0; j < NT; ++j)
      acc1[j] = __builtin_amdgcn_mfma_f32_32x32x16_f16(Au1.v, B[ks & 1][j], acc1[j], 0, 0, 0);
    const int nks = (ks + 2 < KTOT) ? (ks + 2) : (KTOT - 1);  // clamp: dead loads
    #pragma unroll
    for (int j = 0; j < NT; ++j)
      B[ks & 1][j] = bp[(nks*NT + j)*64];
  }

  // ---- epilogue: C/D col=lane&31, row=(reg&3)+8*(reg>>2)+4*(lane>>5) ----
  #pragma unroll
  for (int j = 0; j < NT; ++j) {
    int col = j*32 + ln;
    if (col < O) {
      float bv = bias[col];
      #pragma unroll
      for (int r = 0; r < 16; ++r) {
        int row = (r & 3) + 8*(r >> 2) + 4*kh;
        hout0[row*SOUT + col] = (_Float16)(acc0[j][r] + bv);
        hout1[row*SOUT + col] = (_Float16)(acc1[j][r] + bv);
      }
    }
  }
}

// ---------------------------------------------------------------------------
// fused forward: 2 waves/block x 64 rows (2 tiles) each; zero barriers.
// 1024 waves total (1/SIMD), per-CU B-load count HALVED vs R0.
// LDS = 51200 B -> 2 blocks/CU; grid 512 = exact.
// ---------------------------------------------------------------------------
extern "C" __global__ void __launch_bounds__(128, 1)
kan_forward(const float* __restrict__ x, const float* __restrict__ b_in,
            const float* __restrict__ W_out, const _Float16* __restrict__ wt,
            const float* __restrict__ bias0a, const float* __restrict__ bias0b,
            const float* __restrict__ bias1a, const float* __restrict__ bias1b,
            float* __restrict__ out) {
  __shared__ _Float16 hM[2][2][HM_SLICE];   // [wave][tile]
  __shared__ _Float16 hH[2][2][32*SH];
  const int t    = threadIdx.x;
  const int wv   = t >> 6;                  // 0..1
  const int lane = t & 63;
  const int ln   = lane & 31;
  const int kh   = lane >> 5;
  _Float16* hM0 = hM[wv][0];
  _Float16* hM1 = hM[wv][1];
  _Float16* hH0 = hH[wv][0];
  _Float16* hH1 = hH[wv][1];
  const int rbase = blockIdx.x * TB + wv * 64;   // tile0 rows, tile1 = +32

  // zero hM spots padded reads can touch (per tile): col 129 each row + tail
  hM0[32*SM + lane] = (_Float16)0.0f;
  hM1[32*SM + lane] = (_Float16)0.0f;
  if (lane < 32) { hM0[lane*SM + 129] = (_Float16)0.0f; hM1[lane*SM + 129] = (_Float16)0.0f; }

  // stage 1: hH = relu(x @ W_in + b_in). Two k-steps, 2 n-tiles, 2 row-tiles.
  {
    const half8* bp = (const half8*)wt + lane;
    #pragma unroll
    for (int tt = 0; tt < 2; ++tt) {
      const float* xr = &x[(size_t)(rbase + tt*32 + ln)*32 + kh*8];
      float4 v0 = *(const float4*)&xr[0];
      float4 v1 = *(const float4*)&xr[4];
      float4 v2 = *(const float4*)&xr[16];
      float4 v3 = *(const float4*)&xr[20];
      union { fp16x2 h2[4]; half8 h8; } A0, A1;
      A0.h2[0] = __builtin_amdgcn_cvt_pkrtz(v0.x, v0.y);
      A0.h2[1] = __builtin_amdgcn_cvt_pkrtz(v0.z, v0.w);
      A0.h2[2] = __builtin_amdgcn_cvt_pkrtz(v1.x, v1.y);
      A0.h2[3] = __builtin_amdgcn_cvt_pkrtz(v1.z, v1.w);
      A1.h2[0] = __builtin_amdgcn_cvt_pkrtz(v2.x, v2.y);
      A1.h2[1] = __builtin_amdgcn_cvt_pkrtz(v2.z, v2.w);
      A1.h2[2] = __builtin_amdgcn_cvt_pkrtz(v3.x, v3.y);
      A1.h2[3] = __builtin_amdgcn_cvt_pkrtz(v3.z, v3.w);
      _Float16* hHt = (tt == 0) ? hH0 : hH1;
      #pragma unroll
      for (int nt = 0; nt < 2; ++nt) {
        floatx16 a;
        #pragma unroll
        for (int e = 0; e < 16; ++e) a[e] = 0.0f;
        a = __builtin_amdgcn_mfma_f32_32x32x16_f16(A0.h8, bp[nt*64],       a, 0, 0, 0);
        a = __builtin_amdgcn_mfma_f32_32x32x16_f16(A1.h8, bp[(2 + nt)*64], a, 0, 0, 0);
        int col = nt*32 + ln;
        float bv = b_in[col];
        #pragma unroll
        for (int r = 0; r < 16; ++r) {
          int row = (r & 3) + 8*(r >> 2) + 4*kh;
          hHt[row*SH + col] = (_Float16)fmaxf(a[r] + bv, 0.0f);
        }
      }
    }
  }

  kan_layer2<32,4,5,SH,129,SM>(hH0, hH1, hM0, hM1, wt + WIN,             bias0a, lane);
  kan_layer2<65,9,2,SM, 64,SH>(hM0, hM1, hH0, hH1, wt + WIN + WA,        bias0b, lane);
  kan_layer2<32,4,5,SH,129,SM>(hH0, hH1, hM0, hM1, wt + WIN + WA + WB,   bias1a, lane);
  kan_layer2<65,9,2,SM, 64,SH>(hM0, hM1, hH0, hH1, wt + WIN + 2*WA + WB, bias1b, lane);

  // final: out = sigmoid(hH @ W_out); per tile, two col-halves shuffle-reduced
  #pragma unroll
  for (int tt = 0; tt < 2; ++tt) {
    const _Float16* hHt = (tt == 0) ? hH0 : hH1;
    float s = 0.0f;
    #pragma unroll
    for (int j = 0; j < 32; ++j)
      s = fmaf((float)hHt[ln*SH + kh*32 + j], W_out[kh*32 + j], s);
    s += __shfl_down(s, 32);
    if (lane < 32)
      out[rbase + tt*32 + ln] = __builtin_amdgcn_rcpf(1.0f + __expf(-s));
  }
}

// ---------------------------------------------------------------------------
extern "C" void kernel_launch(void* const* d_in, const int* in_sizes, int n_in,
                              void* d_out, int out_size, void* d_ws, size_t ws_size,
                              hipStream_t stream) {
  const float* x     = (const float*)d_in[0];
  const float* W_in  = (const float*)d_in[1];
  const float* b_in  = (const float*)d_in[2];
  const float* W_out = (const float*)d_in[3];
  const float* c0a = (const float*)d_in[4];  const float* sb0a = (const float*)d_in[5];
  const float* ss0a= (const float*)d_in[6];  const float* bias0a=(const float*)d_in[7];
  const float* c0b = (const float*)d_in[8];  const float* sb0b = (const float*)d_in[9];
  const float* ss0b= (const float*)d_in[10]; const float* bias0b=(const float*)d_in[11];
  const float* c1a = (const float*)d_in[12]; const float* sb1a = (const float*)d_in[13];
  const float* ss1a= (const float*)d_in[14]; const float* bias1a=(const float*)d_in[15];
  const float* c1b = (const float*)d_in[16]; const float* sb1b = (const float*)d_in[17];
  const float* ss1b= (const float*)d_in[18]; const float* bias1b=(const float*)d_in[19];
  float*    out = (float*)d_out;
  _Float16* wt  = (_Float16*)d_ws;       // 675,840 B scratch, repacked every call

  setup_weights<<<(WTOT + 255)/256, 256, 0, stream>>>(
      W_in, c0a, sb0a, ss0a, c0b, sb0b, ss0b,
      c1a, sb1a, ss1a, c1b, sb1b, ss1b, wt);

  kan_forward<<<BATCH/TB, 128, 0, stream>>>(
      x, b_in, W_out, wt, bias0a, bias0b, bias1a, bias1b, out);
}

// Round 10
// 153.504 us; speedup vs baseline: 1.0430x; 1.0430x over previous
//
#include <hip/hip_runtime.h>
#include <math.h>
#include <stdint.h>

// ---------------- model constants ----------------
#define BATCH 65536
#define TB 128           // 4 waves x 32 rows (one 32x32 m-tile each), independent

typedef __fp16   fp16x2  __attribute__((ext_vector_type(2)));   // cvt_pkrtz result
typedef _Float16 half4   __attribute__((ext_vector_type(4)));
typedef _Float16 half8   __attribute__((ext_vector_type(8)));
typedef float    floatx16 __attribute__((ext_vector_type(16)));

// per-wave LDS strides (halves)
#define SH 68            // hH: 64 cols + 4 pad
#define SM 130           // hM: 129 cols + 1
#define HM_SLICE (32*SM + 64)   // +64 zeroed tail halves (overrun reads, row 31)

// packed-weight geometry (f16), FRAGMENT-ORDERED for 32x32x16 (same as R0):
//   element (ks, nt, lane, j) at ((ks*NT + nt)*512) + lane*8 + j
//   maps to B[k = ks*16 + (lane>>5)*8 + j][n = nt*32 + (lane&31)]
#define WIN 2048          // stage1: 2 ksteps x 2 ntiles x 512
#define KSA 36            // a: 32 spline ksteps + 4 silu
#define KSB 74            // b: 65 spline ksteps (1032 real k) + 9 silu (129 real)
#define WA (KSA*5*512)    // 92160
#define WB (KSB*2*512)    // 75776
#define WTOT (WIN + 2*(WA+WB))   // 337920 halfs = 675840 B of d_ws

// ---------------------------------------------------------------------------
// setup: pack all weights f16 in 32x32-fragment order (unchanged from R0).
// ---------------------------------------------------------------------------
__global__ void setup_weights(
    const float* __restrict__ W_in,
    const float* __restrict__ c0a, const float* __restrict__ sb0a, const float* __restrict__ ss0a,
    const float* __restrict__ c0b, const float* __restrict__ sb0b, const float* __restrict__ ss0b,
    const float* __restrict__ c1a, const float* __restrict__ sb1a, const float* __restrict__ ss1a,
    const float* __restrict__ c1b, const float* __restrict__ sb1b, const float* __restrict__ ss1b,
    _Float16* __restrict__ wt) {
  int idx = blockIdx.x * 256 + threadIdx.x;
  if (idx >= WTOT) return;
  float v = 0.0f;
  if (idx < WIN) {                        // W_in [32][64]: (ks*2+nt)*512 order
    int ks = idx >> 10; int nt = (idx >> 9) & 1;
    int q = idx & 511;  int l = q >> 3;   int j = q & 7;
    int n = nt*32 + (l & 31);
    int k = ks*16 + (l >> 5)*8 + j;
    v = W_in[k*64 + n];
  } else {
    int e2   = idx - WIN;
    int pair = (e2 >= WA + WB) ? 1 : 0;
    int e    = e2 - pair * (WA + WB);
    if (e < WA) {                         // a-type: I=64, O=129 (5 n-tiles)
      const float* coef = pair ? c1a : c0a;
      const float* sb   = pair ? sb1a : sb0a;
      const float* ss   = pair ? ss1a : ss0a;
      int ks = e / 2560; int r = e - ks*2560;
      int nt = r >> 9;   int q = r & 511;
      int l  = q >> 3;   int j = q & 7;
      int n  = nt*32 + (l & 31);
      int k  = ks*16 + (l >> 5)*8 + j;    // k < 576
      if (n < 129) {
        if (k < 512) { int i = k >> 3, p = k & 7; v = ss[i*129+n] * coef[(i*129+n)*8 + p]; }
        else         { int i = k - 512; if (i < 64) v = sb[i*129+n]; }
      }
    } else {                              // b-type: I=129, O=64 (2 n-tiles)
      const float* coef = pair ? c1b : c0b;
      const float* sb   = pair ? sb1b : sb0b;
      const float* ss   = pair ? ss1b : ss0b;
      int eb = e - WA;
      int ks = eb >> 10; int r = eb & 1023;
      int nt = r >> 9;   int q = r & 511;
      int l  = q >> 3;   int j = q & 7;
      int n  = nt*32 + (l & 31);
      int k  = ks*16 + (l >> 5)*8 + j;    // k < 1184
      if (k < 1032)      { int i = k >> 3, p = k & 7; v = ss[i*64+n] * coef[(i*64+n)*8 + p]; }
      else if (k >= 1040){ int s = k - 1040; if (s < 129) v = sb[s*64+n]; }
      // k in [1032,1040) and s >= 129: dead pad slots -> 0
    }
  }
  wt[idx] = (_Float16)v;
}

// ---------------------------------------------------------------------------
// feat8: 8 B-spline basis values of x as a ready A-fragment (R0, unchanged).
// ---------------------------------------------------------------------------
__device__ __forceinline__ half8 feat8(float x) {
  float s  = fmaf(x, 2.5f, 5.5f);          // (x+2.2)*2.5
  float mf = floorf(s);
  int   m  = (int)mf;
  float u  = s - mf;
  float t  = 1.0f - u;
  float u2 = u*u;
  float t2 = t*t;
  float w0 = t2 * (t * (1.0f/6.0f));
  float w3 = u2 * (u * (1.0f/6.0f));
  float w1 = fmaf(u2, fmaf(0.5f, u, -1.0f), 2.0f/3.0f);   // (3u^3-6u^2+4)/6
  float w2 = fmaf(t2, fmaf(0.5f, t, -1.0f), 2.0f/3.0f);   // symmetry: w1(t)
  union { fp16x2 h2[2]; uint64_t u64; } P;
  P.h2[0] = __builtin_amdgcn_cvt_pkrtz(w0, w1);
  P.h2[1] = __builtin_amdgcn_cvt_pkrtz(w2, w3);
  uint64_t T = ((unsigned)m <= 10u) ? P.u64 : 0ull;
  int A = (m << 4) - 48;                   // bit pos of T in 128-bit window
  uint64_t L  = T << (A & 63);             // valid A: {-48..112} step 16
  uint64_t R_ = T >> ((-A) & 63);
  uint64_t q0 = (A >= 0) ? ((A < 64) ? L : 0ull) : R_;
  uint64_t q1 = (A >= 64) ? L : ((A > 0) ? R_ : 0ull);
  union { uint64_t q[2]; half8 h; } R;
  R.q[0] = q0; R.q[1] = q1;
  return R.h;
}

// extract half #kh of dword w (khs = kh*16), as f32
__device__ __forceinline__ float extract_half(uint32_t w, int khs) {
  union { uint32_t u; _Float16 h[2]; } cv;
  cv.u = w >> khs;
  return (float)cv.h[0];
}

// cheap silu: x * rcp(1+exp(-x))
__device__ __forceinline__ float silu(float x) {
  return x * __builtin_amdgcn_rcpf(1.0f + __expf(-x));
}

// ---------------------------------------------------------------------------
// one KAN layer, per-wave 32 rows = one 32x32 m-tile. SAME math/order as R0,
// but CODE-COMPACT: spline ksteps as a rolled pair-loop (#pragma unroll 1,
// named B0/B1 slots — no runtime-indexed arrays), silu tail unrolled
// (compile-time slot parity). Inlined ONCE per layer type via the caller's
// l-loop -> hot code fits L1I (I-fetch theory, R10).
// ---------------------------------------------------------------------------
template<int KSPL, int KSIL, int NT, int SIN, int O, int SOUT>
__device__ __forceinline__ void kan_layer(
    const _Float16* __restrict__ hinw, _Float16* __restrict__ houtw,
    const _Float16* __restrict__ wtl, const float* __restrict__ bias, int lane) {
  constexpr int KTOT  = KSPL + KSIL;
  constexpr int NPAIR = KSPL / 2;
  constexpr int REM   = KSPL & 1;          // layer-b: 1
  const int ln  = lane & 31;
  const int kh  = lane >> 5;
  const int khs = kh << 4;
  const half8* __restrict__ bp = (const half8*)wtl + lane;   // +lane*16B
  floatx16 acc[NT];
  #pragma unroll
  for (int j = 0; j < NT; ++j)
    #pragma unroll
    for (int e = 0; e < 16; ++e) acc[j][e] = 0.0f;

  half8 B0[NT], B1[NT];                    // depth-2, zero-copy slots
  #pragma unroll
  for (int j = 0; j < NT; ++j) B0[j] = bp[j*64];
  #pragma unroll
  for (int j = 0; j < NT; ++j) B1[j] = bp[(NT + j)*64];

  // ---- spline pairs: ksteps 2c (B0), 2c+1 (B1); inputs 4c+kh, 4c+2+kh ----
  #pragma unroll 1
  for (int c = 0; c < NPAIR; ++c) {
    union { half4 v; uint32_t d[2]; } hq;
    hq.v = *(const half4*)&hinw[ln*SIN + 4*c];
    half8 A0 = feat8(extract_half(hq.d[0], khs));
    half8 A1 = feat8(extract_half(hq.d[1], khs));
    #pragma unroll
    for (int j = 0; j < NT; ++j)
      acc[j] = __builtin_amdgcn_mfma_f32_32x32x16_f16(A0, B0[j], acc[j], 0, 0, 0);
    #pragma unroll
    for (int j = 0; j < NT; ++j) B0[j] = bp[((2*c + 2)*NT + j)*64];
    #pragma unroll
    for (int j = 0; j < NT; ++j)
      acc[j] = __builtin_amdgcn_mfma_f32_32x32x16_f16(A1, B1[j], acc[j], 0, 0, 0);
    #pragma unroll
    for (int j = 0; j < NT; ++j) B1[j] = bp[((2*c + 3)*NT + j)*64];  // <= KSPL+1 <= KTOT-1
  }

  // ---- remainder spline step (layer-b: ks = KSPL-1, even -> B0) ----
  if constexpr (REM) {
    constexpr int ks = KSPL - 1;
    uint32_t w = *(const uint32_t*)&hinw[ln*SIN + 2*ks];
    half8 A = feat8(extract_half(w, khs));
    #pragma unroll
    for (int j = 0; j < NT; ++j)
      acc[j] = __builtin_amdgcn_mfma_f32_32x32x16_f16(A, B0[j], acc[j], 0, 0, 0);
    #pragma unroll
    for (int j = 0; j < NT; ++j) B0[j] = bp[((ks + 2)*NT + j)*64];   // ks+2 < KTOT
  }

  // ---- silu k-steps (unrolled; compile-time slot parity, R0 order) ----
  #pragma unroll
  for (int sk = 0; sk < KSIL; ++sk) {
    const int ks = KSPL + sk;
    half8 h8 = *(const half8*)&hinw[ln*SIN + sk*16 + kh*8];
    union { fp16x2 h2[4]; half8 v; } Au;
    #pragma unroll
    for (int e = 0; e < 4; ++e) {
      float s0 = silu((float)h8[2*e]);
      float s1 = silu((float)h8[2*e + 1]);
      Au.h2[e] = __builtin_amdgcn_cvt_pkrtz(s0, s1);
    }
    const int nks = (ks + 2 < KTOT) ? (ks + 2) : (KTOT - 1);  // clamp: dead loads
    if ((ks & 1) == 0) {
      #pragma unroll
      for (int j = 0; j < NT; ++j)
        acc[j] = __builtin_amdgcn_mfma_f32_32x32x16_f16(Au.v, B0[j], acc[j], 0, 0, 0);
      #pragma unroll
      for (int j = 0; j < NT; ++j) B0[j] = bp[(nks*NT + j)*64];
    } else {
      #pragma unroll
      for (int j = 0; j < NT; ++j)
        acc[j] = __builtin_amdgcn_mfma_f32_32x32x16_f16(Au.v, B1[j], acc[j], 0, 0, 0);
      #pragma unroll
      for (int j = 0; j < NT; ++j) B1[j] = bp[(nks*NT + j)*64];
    }
  }

  // ---- epilogue: C/D col=lane&31, row=(reg&3)+8*(reg>>2)+4*(lane>>5) ----
  #pragma unroll
  for (int j = 0; j < NT; ++j) {
    int col = j*32 + ln;
    if (col < O) {
      float bv = bias[col];
      #pragma unroll
      for (int r = 0; r < 16; ++r) {
        int row = (r & 3) + 8*(r >> 2) + 4*kh;
        houtw[row*SOUT + col] = (_Float16)(acc[j][r] + bv);
      }
    }
  }
}

// ---------------------------------------------------------------------------
// fused forward: R0 structure, zero barriers; layer code exists ONCE via the
// l-loop (layer-a + layer-b bodies each a single copy -> ~8x less code).
// LDS = 51200 B -> 2 blocks/CU; grid 512 = exact.
// ---------------------------------------------------------------------------
extern "C" __global__ void __launch_bounds__(256, 2)
kan_forward(const float* __restrict__ x, const float* __restrict__ b_in,
            const float* __restrict__ W_out, const _Float16* __restrict__ wt,
            const float* __restrict__ bias0a, const float* __restrict__ bias0b,
            const float* __restrict__ bias1a, const float* __restrict__ bias1b,
            float* __restrict__ out) {
  __shared__ _Float16 hM[4][HM_SLICE];
  __shared__ _Float16 hH[4][32*SH];
  const int t    = threadIdx.x;
  const int wv   = t >> 6;
  const int lane = t & 63;
  const int ln   = lane & 31;
  const int kh   = lane >> 5;
  _Float16* hMw = hM[wv];
  _Float16* hHw = hH[wv];
  const int rbase = blockIdx.x * TB + wv * 32;

  // zero hM spots padded reads can touch: col 129 each row + tail pad
  hMw[32*SM + lane] = (_Float16)0.0f;
  if (lane < 32) hMw[lane*SM + 129] = (_Float16)0.0f;

  // stage 1: hH = relu(x @ W_in + b_in). Two k-steps, 2 n-tiles.
  {
    const float* xr = &x[(rbase + ln)*32 + kh*8];
    float4 v0 = *(const float4*)&xr[0];
    float4 v1 = *(const float4*)&xr[4];
    float4 v2 = *(const float4*)&xr[16];
    float4 v3 = *(const float4*)&xr[20];
    union { fp16x2 h2[4]; half8 h8; } A0, A1;
    A0.h2[0] = __builtin_amdgcn_cvt_pkrtz(v0.x, v0.y);
    A0.h2[1] = __builtin_amdgcn_cvt_pkrtz(v0.z, v0.w);
    A0.h2[2] = __builtin_amdgcn_cvt_pkrtz(v1.x, v1.y);
    A0.h2[3] = __builtin_amdgcn_cvt_pkrtz(v1.z, v1.w);
    A1.h2[0] = __builtin_amdgcn_cvt_pkrtz(v2.x, v2.y);
    A1.h2[1] = __builtin_amdgcn_cvt_pkrtz(v2.z, v2.w);
    A1.h2[2] = __builtin_amdgcn_cvt_pkrtz(v3.x, v3.y);
    A1.h2[3] = __builtin_amdgcn_cvt_pkrtz(v3.z, v3.w);
    const half8* bp = (const half8*)wt + lane;
    #pragma unroll
    for (int nt = 0; nt < 2; ++nt) {
      floatx16 a;
      #pragma unroll
      for (int e = 0; e < 16; ++e) a[e] = 0.0f;
      a = __builtin_amdgcn_mfma_f32_32x32x16_f16(A0.h8, bp[nt*64],       a, 0, 0, 0);
      a = __builtin_amdgcn_mfma_f32_32x32x16_f16(A1.h8, bp[(2 + nt)*64], a, 0, 0, 0);
      int col = nt*32 + ln;
      float bv = b_in[col];
      #pragma unroll
      for (int r = 0; r < 16; ++r) {
        int row = (r & 3) + 8*(r >> 2) + 4*kh;
        hHw[row*SH + col] = (_Float16)fmaxf(a[r] + bv, 0.0f);
      }
    }
  }

  // two KAN blocks; layer-a and layer-b code each emitted ONCE
  #pragma unroll 1
  for (int l = 0; l < 2; ++l) {
    const _Float16* wtl = wt + WIN + l*(WA + WB);
    const float* ba = l ? bias1a : bias0a;
    const float* bb = l ? bias1b : bias0b;
    kan_layer<32,4,5,SH,129,SM>(hHw, hMw, wtl,      ba, lane);
    kan_layer<65,9,2,SM, 64,SH>(hMw, hHw, wtl + WA, bb, lane);
  }

  // final: out = sigmoid(hH @ W_out); two col-halves reduced by shuffle
  {
    float s = 0.0f;
    #pragma unroll
    for (int j = 0; j < 32; ++j)
      s = fmaf((float)hHw[ln*SH + kh*32 + j], W_out[kh*32 + j], s);
    s += __shfl_down(s, 32);
    if (lane < 32)
      out[rbase + ln] = __builtin_amdgcn_rcpf(1.0f + __expf(-s));
  }
}

// ---------------------------------------------------------------------------
extern "C" void kernel_launch(void* const* d_in, const int* in_sizes, int n_in,
                              void* d_out, int out_size, void* d_ws, size_t ws_size,
                              hipStream_t stream) {
  const float* x     = (const float*)d_in[0];
  const float* W_in  = (const float*)d_in[1];
  const float* b_in  = (const float*)d_in[2];
  const float* W_out = (const float*)d_in[3];
  const float* c0a = (const float*)d_in[4];  const float* sb0a = (const float*)d_in[5];
  const float* ss0a= (const float*)d_in[6];  const float* bias0a=(const float*)d_in[7];
  const float* c0b = (const float*)d_in[8];  const float* sb0b = (const float*)d_in[9];
  const float* ss0b= (const float*)d_in[10]; const float* bias0b=(const float*)d_in[11];
  const float* c1a = (const float*)d_in[12]; const float* sb1a = (const float*)d_in[13];
  const float* ss1a= (const float*)d_in[14]; const float* bias1a=(const float*)d_in[15];
  const float* c1b = (const float*)d_in[16]; const float* sb1b = (const float*)d_in[17];
  const float* ss1b= (const float*)d_in[18]; const float* bias1b=(const float*)d_in[19];
  float*    out = (float*)d_out;
  _Float16* wt  = (_Float16*)d_ws;       // 675,840 B scratch, repacked every call

  setup_weights<<<(WTOT + 255)/256, 256, 0, stream>>>(
      W_in, c0a, sb0a, ss0a, c0b, sb0b, ss0b,
      c1a, sb1a, ss1a, c1b, sb1b, ss1b, wt);

  kan_forward<<<BATCH/TB, 256, 0, stream>>>(
      x, b_in, W_out, wt, bias0a, bias0b, bias1a, bias1b, out);
}